// Round 1
// baseline (1518.254 us; speedup 1.0000x reference)
//
#include <hip/hip_runtime.h>
#include <math.h>

#define NB 8          // batch
#define NC 3          // channels
#define PD 192        // feature dim = 3*8*8
#define IMG 512
#define NP 169        // patches per spatial dim
#define NPATCH 28561  // NP*NP
#define INV_N (1.0f/28561.0f)

typedef float f4 __attribute__((ext_vector_type(4)));
typedef f4 f4u __attribute__((aligned(4)));   // 4B-aligned vector load type

// ---------------- per-feature patch sums (for the mean) ----------------
__global__ __launch_bounds__(256) void row_sums_k(const float* __restrict__ x,
                                                  float* __restrict__ S) {
  int bid = blockIdx.x;            // b*PD + d
  int b = bid / PD, d = bid - b * PD;
  int c = d >> 6, ii = (d >> 3) & 7, jj = d & 7;
  const float* img = x + ((size_t)(b * NC + c)) * (IMG * IMG);
  float part = 0.f;
  for (int p = threadIdx.x; p < NPATCH; p += 256) {
    int ph = p / NP;
    int pw = p - ph * NP;
    part += img[(3 * ph + ii) * IMG + 3 * pw + jj];
  }
  __shared__ float red[256];
  int t = threadIdx.x;
  red[t] = part; __syncthreads();
  for (int s = 128; s > 0; s >>= 1) { if (t < s) red[t] += red[t + s]; __syncthreads(); }
  if (t == 0) S[bid] = red[0];
}

// ---------------- split-K Gram matrix: partial[chunk][b][192][192] ----------------
__global__ __launch_bounds__(256, 2) void cov_gemm_k(const float* __restrict__ x,
                                                     float* __restrict__ partial,
                                                     int CH, int chunkSize) {
  int chunk = blockIdx.x % CH;
  int b = blockIdx.x / CH;
  int p0 = chunk * chunkSize;
  int pcount = NPATCH - p0;
  if (pcount > chunkSize) pcount = chunkSize;
  if (pcount < 0) pcount = 0;
  int ntiles = (pcount + 15) >> 4;
  int pend = p0 + pcount;

  __shared__ float As[16][200];    // [k-slice][192 features + pad]

  int t = threadIdx.x;
  int ty = t >> 4, tx = t & 15;
  const float* imgb = x + (size_t)b * NC * IMG * IMG;

  float acc[12][12];
  for (int i = 0; i < 12; ++i)
    for (int j = 0; j < 12; ++j)
      acc[i][j] = 0.f;

  for (int kt = 0; kt < ntiles; ++kt) {
    int pbase = p0 + (kt << 4);
    f4 ld[3];
    int pks[3], dls[3];
#pragma unroll
    for (int l = 0; l < 3; ++l) {
      int f = l * 256 + t;          // 0..767 quad index
      int pk = f / 48;              // 0..15 patch within k-tile
      int rr = f - pk * 48;         // 0..47
      int c  = rr >> 4;             // channel
      int ii = (rr & 15) >> 1;      // patch row offset 0..7
      int j4 = (rr & 1) << 2;       // 0 or 4
      int p = pbase + pk;
      f4 v = {0.f, 0.f, 0.f, 0.f};
      if (p < pend) {
        int ph = p / NP, pw = p - ph * NP;
        const f4u* src = (const f4u*)(imgb + ((size_t)c * IMG + (3 * ph + ii)) * IMG + 3 * pw + j4);
        v = (f4)(*src);
      }
      ld[l] = v;
      pks[l] = pk;
      dls[l] = (c << 6) + (ii << 3) + j4;
    }
    __syncthreads();
#pragma unroll
    for (int l = 0; l < 3; ++l)
      *(f4*)&As[pks[l]][dls[l]] = ld[l];
    __syncthreads();

    for (int kk = 0; kk < 16; ++kk) {
      const f4* ap = (const f4*)&As[kk][ty * 12];
      const f4* bp = (const f4*)&As[kk][tx * 12];
      f4 avq[3], bvq[3];
#pragma unroll
      for (int q = 0; q < 3; ++q) { avq[q] = ap[q]; bvq[q] = bp[q]; }
      float a[12], bb[12];
#pragma unroll
      for (int q = 0; q < 12; ++q) { a[q] = avq[q >> 2][q & 3]; bb[q] = bvq[q >> 2][q & 3]; }
#pragma unroll
      for (int i = 0; i < 12; ++i)
#pragma unroll
        for (int j = 0; j < 12; ++j)
          acc[i][j] += a[i] * bb[j];
    }
  }

  float* outp = partial + ((size_t)chunk * NB + b) * PD * PD;
  for (int i = 0; i < 12; ++i) {
    int m = ty * 12 + i;
    for (int j = 0; j < 12; ++j)
      outp[m * PD + tx * 12 + j] = acc[i][j];
  }
}

// ---------------- reduce partials + finalize covariance ----------------
__global__ __launch_bounds__(256) void reduce_fin_k(const float* __restrict__ partial,
                                                    const float* __restrict__ S,
                                                    float* __restrict__ G, int CH) {
  int e = blockIdx.x * 256 + threadIdx.x;
  const int tot = NB * PD * PD;
  if (e >= tot) return;
  int b = e / (PD * PD);
  int rem = e - b * PD * PD;
  int i = rem / PD, j = rem - i * PD;
  float s = 0.f;
  for (int c = 0; c < CH; ++c) s += partial[((size_t)c * NB + b) * PD * PD + rem];
  float mui = S[b * PD + i] * INV_N, muj = S[b * PD + j] * INV_N;
  G[e] = s * INV_N - mui * muj;
}

// ---------------- eigenvalues (Householder tridiag + Sturm bisection) + threshold ----------------
#define LDA 193
__global__ __launch_bounds__(256) void eigen_k(const float* __restrict__ sigma,
                                               float* __restrict__ out) {
  __shared__ float A[PD * LDA];
  __shared__ float vv[PD], pp[PD], ww[PD];
  __shared__ float dd[PD], ee[PD], e2[PD];
  __shared__ float sig[PD], csum[PD];
  __shared__ float red[256];
  __shared__ int redi[256];

  int b = blockIdx.x, t = threadIdx.x;
  const float* M = sigma + (size_t)b * PD * PD;
  for (int idx = t; idx < PD * PD; idx += 256) {
    int r = idx / PD, c2 = idx - r * PD;
    A[r * LDA + c2] = M[idx];
  }
  __syncthreads();

  // Householder tridiagonalization
  for (int k = 0; k < PD - 2; ++k) {
    int k1 = k + 1;
    int m = PD - k1;
    float part = 0.f;
    for (int i = k1 + t; i < PD; i += 256) { float a = A[i * LDA + k]; part += a * a; }
    red[t] = part; __syncthreads();
    for (int s = 128; s > 0; s >>= 1) { if (t < s) red[t] += red[t + s]; __syncthreads(); }
    float total = red[0];
    float x0 = A[k1 * LDA + k];
    if (total < 1e-32f) {
      if (t == 0) ee[k] = x0;
      __syncthreads();           // protect red[0] before next iteration's write
      continue;
    }
    float nrm = sqrtf(total);
    float alpha = (x0 >= 0.f) ? -nrm : nrm;
    float beta = 1.0f / (total - alpha * x0);   // H = I - beta*v*v^T
    for (int i = t; i < m; i += 256)
      vv[i] = (i == 0) ? (x0 - alpha) : A[(k1 + i) * LDA + k];
    if (t == 0) ee[k] = alpha;
    __syncthreads();
    if (t < m) {
      const float* row = &A[(k1 + t) * LDA + k1];
      float s0 = 0, s1 = 0, s2 = 0, s3 = 0;
      int j = 0;
      for (; j + 3 < m; j += 4) {
        s0 += row[j    ] * vv[j    ];
        s1 += row[j + 1] * vv[j + 1];
        s2 += row[j + 2] * vv[j + 2];
        s3 += row[j + 3] * vv[j + 3];
      }
      for (; j < m; ++j) s0 += row[j] * vv[j];
      pp[t] = beta * ((s0 + s1) + (s2 + s3));
    }
    __syncthreads();
    part = 0.f;
    for (int i = t; i < m; i += 256) part += pp[i] * vv[i];
    red[t] = part; __syncthreads();
    for (int s = 128; s > 0; s >>= 1) { if (t < s) red[t] += red[t + s]; __syncthreads(); }
    float Kc = 0.5f * beta * red[0];
    __syncthreads();
    for (int i = t; i < m; i += 256) ww[i] = pp[i] - Kc * vv[i];
    __syncthreads();
    if (t < m) {
      float vr = vv[t], wr = ww[t];
      float* row = &A[(k1 + t) * LDA + k1];
      int j = 0;
      for (; j + 3 < m; j += 4) {
        row[j    ] -= vr * ww[j    ] + wr * vv[j    ];
        row[j + 1] -= vr * ww[j + 1] + wr * vv[j + 1];
        row[j + 2] -= vr * ww[j + 2] + wr * vv[j + 2];
        row[j + 3] -= vr * ww[j + 3] + wr * vv[j + 3];
      }
      for (; j < m; ++j) row[j] -= vr * ww[j] + wr * vv[j];
    }
    __syncthreads();
  }

  for (int i = t; i < PD; i += 256) dd[i] = A[i * LDA + i];
  if (t == 0) ee[PD - 2] = A[(PD - 1) * LDA + (PD - 2)];
  __syncthreads();
  for (int i = t; i < PD - 1; i += 256) e2[i] = ee[i] * ee[i];
  __syncthreads();

  // Gershgorin bounds
  float glo = 1e30f, ghi = -1e30f;
  for (int i = t; i < PD; i += 256) {
    float r = 0.f;
    if (i > 0) r += fabsf(ee[i - 1]);
    if (i < PD - 1) r += fabsf(ee[i]);
    glo = fminf(glo, dd[i] - r);
    ghi = fmaxf(ghi, dd[i] + r);
  }
  red[t] = glo; __syncthreads();
  for (int s = 128; s > 0; s >>= 1) { if (t < s) red[t] = fminf(red[t], red[t + s]); __syncthreads(); }
  glo = red[0]; __syncthreads();
  red[t] = ghi; __syncthreads();
  for (int s = 128; s > 0; s >>= 1) { if (t < s) red[t] = fmaxf(red[t], red[t + s]); __syncthreads(); }
  ghi = red[0]; __syncthreads();
  float wid = ghi - glo;
  glo -= 1e-3f * wid + 1e-20f;
  ghi += 1e-3f * wid + 1e-20f;

  // bisection: thread t finds the t-th smallest eigenvalue
  if (t < PD) {
    float l = glo, h = ghi;
    for (int it = 0; it < 42; ++it) {
      float mid = 0.5f * (l + h);
      if (mid <= l || mid >= h) break;     // fp32-converged
      int cnt = 0;
      float q = 1.0f;
      for (int i = 0; i < PD; ++i) {
        float term = (i > 0) ? e2[i - 1] * __builtin_amdgcn_rcpf(q) : 0.0f;
        q = (dd[i] - mid) - term;
        cnt += (q < 0.f);
        float aq = fabsf(q);
        if (aq < 1e-30f) q = (q < 0.f) ? -1e-30f : 1e-30f;
      }
      if (cnt > t) h = mid; else l = mid;
    }
    sig[t] = 0.5f * (l + h);
  }
  __syncthreads();

  // threshold search (mirror of the reference's vectorized loop)
  if (t == 0) {
    float c = 0.f;
    for (int i = 0; i < PD; ++i) { c += sig[i]; csum[i] = c; }
  }
  __syncthreads();
  float tau = 0.f;
  int vk = 1 << 30;
  if (t < PD) {
    int L = PD - 1 - t;
    tau = (L > 0) ? csum[L - 1] / (float)L : 0.0f;
    int gt = 0, lt2 = 0;
    for (int j = 0; j < L; ++j) {
      float sv = sig[j];
      gt  += (sv > tau);
      lt2 += (sv < tau);
    }
    if (gt == lt2) vk = t;
  }
  redi[t] = vk; __syncthreads();
  for (int s = 128; s > 0; s >>= 1) { if (t < s) redi[t] = min(redi[t], redi[t + s]); __syncthreads(); }
  if (t == redi[0]) out[b] = sqrtf(fmaxf(tau, 0.f));
}

extern "C" void kernel_launch(void* const* d_in, const int* in_sizes, int n_in,
                              void* d_out, int out_size, void* d_ws, size_t ws_size,
                              hipStream_t stream) {
  const float* x = (const float*)d_in[0];
  float* out = (float*)d_out;

  size_t gElems = (size_t)NB * PD * PD;       // 294912
  int CH = 64;
  while (CH > 1 && ws_size < ((size_t)CH + 1) * gElems * 4 + (size_t)NB * PD * 4)
    CH >>= 1;
  float* G = (float*)d_ws;
  float* partial = G + gElems;
  float* S = partial + (size_t)CH * gElems;
  int chunkSize = (NPATCH + CH - 1) / CH;

  row_sums_k<<<NB * PD, 256, 0, stream>>>(x, S);
  cov_gemm_k<<<NB * CH, 256, 0, stream>>>(x, partial, CH, chunkSize);
  reduce_fin_k<<<(int)((gElems + 255) / 256), 256, 0, stream>>>(partial, S, G, CH);
  eigen_k<<<NB, 256, 0, stream>>>(G, out);
}

// Round 2
// 1104.809 us; speedup vs baseline: 1.3742x; 1.3742x over previous
//
#include <hip/hip_runtime.h>
#include <math.h>

#define NB 8          // batch
#define NC 3          // channels
#define PD 192        // feature dim = 3*8*8
#define IMG 512
#define NP 169        // patches per spatial dim
#define NPATCH 28561  // NP*NP
#define INV_N (1.0f/28561.0f)

typedef float f4 __attribute__((ext_vector_type(4)));
typedef f4 f4u __attribute__((aligned(4)));   // 4B-aligned vector load type

// ---------------- per-feature patch sums (for the mean) ----------------
__global__ __launch_bounds__(256) void row_sums_k(const float* __restrict__ x,
                                                  float* __restrict__ S) {
  int bid = blockIdx.x;            // b*PD + d
  int b = bid / PD, d = bid - b * PD;
  int c = d >> 6, ii = (d >> 3) & 7, jj = d & 7;
  const float* img = x + ((size_t)(b * NC + c)) * (IMG * IMG);
  float part = 0.f;
  for (int p = threadIdx.x; p < NPATCH; p += 256) {
    int ph = p / NP;
    int pw = p - ph * NP;
    part += img[(3 * ph + ii) * IMG + 3 * pw + jj];
  }
  __shared__ float red[256];
  int t = threadIdx.x;
  red[t] = part; __syncthreads();
  for (int s = 128; s > 0; s >>= 1) { if (t < s) red[t] += red[t + s]; __syncthreads(); }
  if (t == 0) S[bid] = red[0];
}

// ---------------- split-K Gram matrix: partial[chunk][b][192][192] ----------------
__global__ __launch_bounds__(256, 2) void cov_gemm_k(const float* __restrict__ x,
                                                     float* __restrict__ partial,
                                                     int CH, int chunkSize) {
  int chunk = blockIdx.x % CH;
  int b = blockIdx.x / CH;
  int p0 = chunk * chunkSize;
  int pcount = NPATCH - p0;
  if (pcount > chunkSize) pcount = chunkSize;
  if (pcount < 0) pcount = 0;
  int ntiles = (pcount + 15) >> 4;
  int pend = p0 + pcount;

  __shared__ float As[16][200];    // [k-slice][192 features + pad]

  int t = threadIdx.x;
  int ty = t >> 4, tx = t & 15;
  const float* imgb = x + (size_t)b * NC * IMG * IMG;

  float acc[12][12];
  for (int i = 0; i < 12; ++i)
    for (int j = 0; j < 12; ++j)
      acc[i][j] = 0.f;

  for (int kt = 0; kt < ntiles; ++kt) {
    int pbase = p0 + (kt << 4);
    f4 ld[3];
    int pks[3], dls[3];
#pragma unroll
    for (int l = 0; l < 3; ++l) {
      int f = l * 256 + t;          // 0..767 quad index
      int pk = f / 48;              // 0..15 patch within k-tile
      int rr = f - pk * 48;         // 0..47
      int c  = rr >> 4;             // channel
      int ii = (rr & 15) >> 1;      // patch row offset 0..7
      int j4 = (rr & 1) << 2;       // 0 or 4
      int p = pbase + pk;
      f4 v = {0.f, 0.f, 0.f, 0.f};
      if (p < pend) {
        int ph = p / NP, pw = p - ph * NP;
        const f4u* src = (const f4u*)(imgb + ((size_t)c * IMG + (3 * ph + ii)) * IMG + 3 * pw + j4);
        v = (f4)(*src);
      }
      ld[l] = v;
      pks[l] = pk;
      dls[l] = (c << 6) + (ii << 3) + j4;
    }
    __syncthreads();
#pragma unroll
    for (int l = 0; l < 3; ++l)
      *(f4*)&As[pks[l]][dls[l]] = ld[l];
    __syncthreads();

    for (int kk = 0; kk < 16; ++kk) {
      const f4* ap = (const f4*)&As[kk][ty * 12];
      const f4* bp = (const f4*)&As[kk][tx * 12];
      f4 avq[3], bvq[3];
#pragma unroll
      for (int q = 0; q < 3; ++q) { avq[q] = ap[q]; bvq[q] = bp[q]; }
      float a[12], bb[12];
#pragma unroll
      for (int q = 0; q < 12; ++q) { a[q] = avq[q >> 2][q & 3]; bb[q] = bvq[q >> 2][q & 3]; }
#pragma unroll
      for (int i = 0; i < 12; ++i)
#pragma unroll
        for (int j = 0; j < 12; ++j)
          acc[i][j] += a[i] * bb[j];
    }
  }

  float* outp = partial + ((size_t)chunk * NB + b) * PD * PD;
  for (int i = 0; i < 12; ++i) {
    int m = ty * 12 + i;
    for (int j = 0; j < 12; ++j)
      outp[m * PD + tx * 12 + j] = acc[i][j];
  }
}

// ---------------- reduce partials + finalize covariance ----------------
__global__ __launch_bounds__(256) void reduce_fin_k(const float* __restrict__ partial,
                                                    const float* __restrict__ S,
                                                    float* __restrict__ G, int CH) {
  int e = blockIdx.x * 256 + threadIdx.x;
  const int tot = NB * PD * PD;
  if (e >= tot) return;
  int b = e / (PD * PD);
  int rem = e - b * PD * PD;
  int i = rem / PD, j = rem - i * PD;
  float s = 0.f;
  for (int c = 0; c < CH; ++c) s += partial[((size_t)c * NB + b) * PD * PD + rem];
  float mui = S[b * PD + i] * INV_N, muj = S[b * PD + j] * INV_N;
  G[e] = s * INV_N - mui * muj;
}

// ---------------- eigenvalues (Householder tridiag + Sturm bisection) + threshold ----------------
// v2: f4-vectorized, 3-rows-per-lane with j-chunks split across waves (amortizes
// vv/ww broadcast reads), shuffle reductions, 5 barriers/step.
#define LDAP 196   // row stride in floats: mult of 4 (16B-aligned rows); stride mod 32 = 4
#define NCH (PD/4) // 48 f4 chunks per row
__global__ __launch_bounds__(256) void eigen_k(const float* __restrict__ sigma,
                                               float* __restrict__ out) {
  __shared__ float A[PD * LDAP];
  __shared__ float vvg[PD], wwg[PD];   // global-index space, zero below k1
  __shared__ float ppw[4 * PD];        // per-wave matvec partials
  __shared__ float dd[PD], ee[PD], e2[PD];
  __shared__ float sig[PD], csum[PD];
  __shared__ float red[256];
  __shared__ int redi[256];

  int b = blockIdx.x, t = threadIdx.x;
  int l = t & 63, w = t >> 6;
  const float* M = sigma + (size_t)b * PD * PD;

  // load A (f4, rows 16B-aligned)
  for (int q = t; q < PD * NCH; q += 256) {
    int r = q / NCH, c4 = q - r * NCH;
    *(f4*)&A[r * LDAP + (c4 << 2)] = *(const f4*)&M[r * PD + (c4 << 2)];
  }
  if (t < PD) { vvg[t] = 0.f; wwg[t] = 0.f; }
  __syncthreads();

  // Householder tridiagonalization
  for (int k = 0; k < PD - 2; ++k) {
    int k1 = k + 1;
    int m = PD - k1;
    int r0 = k1 + l, r1 = r0 + 64, r2 = r0 + 128;
    bool h0 = r0 < PD, h1 = r1 < PD, h2 = r2 < PD;
    int c0 = (k1 >> 2) + w;

    // ---- phase 0: extract column k, norm via shuffle (wave 0 only) ----
    if (w == 0) {
      float a0 = 0.f, a1 = 0.f, a2 = 0.f;
      if (h0) { a0 = A[r0 * LDAP + k]; vvg[r0] = a0; }
      if (h1) { a1 = A[r1 * LDAP + k]; vvg[r1] = a1; }
      if (h2) { a2 = A[r2 * LDAP + k]; vvg[r2] = a2; }
      float sq = a0 * a0 + a1 * a1 + a2 * a2;
      for (int off = 32; off > 0; off >>= 1) sq += __shfl_xor(sq, off, 64);
      if (l == 0) {
        float total = sq, x0 = a0;   // lane 0's first row IS k1
        if (total < 1e-32f) {
          ee[k] = x0; red[0] = -1.0f;        // skip flag
        } else {
          float nrm = sqrtf(total);
          float alpha = (x0 >= 0.f) ? -nrm : nrm;
          float bta = 1.0f / (total - alpha * x0);   // H = I - beta*v*v^T
          ee[k] = alpha;
          vvg[k1] = x0 - alpha;
          red[0] = bta;
        }
      }
    }
    if (t == 64) { vvg[k] = 0.f; wwg[k] = 0.f; }   // maintain zero prefix
    __syncthreads();                               // B1
    float beta = red[0];
    if (beta < 0.f) continue;                      // uniform skip

    // ---- phase 1: matvec p = A*v (j-chunks round-robin across waves) ----
    {
      f4 acc0 = {0.f, 0.f, 0.f, 0.f}, acc1 = acc0, acc2 = acc0;
      for (int c = c0; c < NCH; c += 4) {
        f4 v4 = *(const f4*)&vvg[c << 2];
        if (h0) acc0 += *(const f4*)&A[r0 * LDAP + (c << 2)] * v4;
        if (h1) acc1 += *(const f4*)&A[r1 * LDAP + (c << 2)] * v4;
        if (h2) acc2 += *(const f4*)&A[r2 * LDAP + (c << 2)] * v4;
      }
      if (h0) ppw[w * PD + r0] = acc0.x + acc0.y + acc0.z + acc0.w;
      if (h1) ppw[w * PD + r1] = acc1.x + acc1.y + acc1.z + acc1.w;
      if (h2) ppw[w * PD + r2] = acc2.x + acc2.y + acc2.z + acc2.w;
    }
    __syncthreads();                               // B2

    // ---- combine partials, p·v reduction, w = p - K v ----
    float pfull = 0.f, dotp = 0.f;
    int row = k1 + t;
    if (t < m) {
      float s = ppw[row] + ppw[PD + row] + ppw[2 * PD + row] + ppw[3 * PD + row];
      pfull = beta * s;
      dotp = pfull * vvg[row];
    }
    for (int off = 32; off > 0; off >>= 1) dotp += __shfl_xor(dotp, off, 64);
    if (l == 0) red[1 + w] = dotp;
    __syncthreads();                               // B3
    float Kc = 0.5f * beta * (red[1] + red[2] + red[3] + red[4]);
    if (t < m) wwg[row] = pfull - Kc * vvg[row];
    __syncthreads();                               // B4

    // ---- phase 2: rank-2 update A -= v w^T + w v^T ----
    {
      float vr0 = h0 ? vvg[r0] : 0.f, wr0 = h0 ? wwg[r0] : 0.f;
      float vr1 = h1 ? vvg[r1] : 0.f, wr1 = h1 ? wwg[r1] : 0.f;
      float vr2 = h2 ? vvg[r2] : 0.f, wr2 = h2 ? wwg[r2] : 0.f;
      for (int c = c0; c < NCH; c += 4) {
        f4 v4 = *(const f4*)&vvg[c << 2];
        f4 w4 = *(const f4*)&wwg[c << 2];
        if (h0) { f4 a = *(f4*)&A[r0 * LDAP + (c << 2)]; a -= w4 * vr0 + v4 * wr0; *(f4*)&A[r0 * LDAP + (c << 2)] = a; }
        if (h1) { f4 a = *(f4*)&A[r1 * LDAP + (c << 2)]; a -= w4 * vr1 + v4 * wr1; *(f4*)&A[r1 * LDAP + (c << 2)] = a; }
        if (h2) { f4 a = *(f4*)&A[r2 * LDAP + (c << 2)]; a -= w4 * vr2 + v4 * wr2; *(f4*)&A[r2 * LDAP + (c << 2)] = a; }
      }
    }
    __syncthreads();                               // B5
  }

  for (int i = t; i < PD; i += 256) dd[i] = A[i * LDAP + i];
  if (t == 0) ee[PD - 2] = A[(PD - 1) * LDAP + (PD - 2)];
  __syncthreads();
  for (int i = t; i < PD - 1; i += 256) e2[i] = ee[i] * ee[i];
  __syncthreads();

  // Gershgorin bounds
  float glo = 1e30f, ghi = -1e30f;
  for (int i = t; i < PD; i += 256) {
    float r = 0.f;
    if (i > 0) r += fabsf(ee[i - 1]);
    if (i < PD - 1) r += fabsf(ee[i]);
    glo = fminf(glo, dd[i] - r);
    ghi = fmaxf(ghi, dd[i] + r);
  }
  red[t] = glo; __syncthreads();
  for (int s = 128; s > 0; s >>= 1) { if (t < s) red[t] = fminf(red[t], red[t + s]); __syncthreads(); }
  glo = red[0]; __syncthreads();
  red[t] = ghi; __syncthreads();
  for (int s = 128; s > 0; s >>= 1) { if (t < s) red[t] = fmaxf(red[t], red[t + s]); __syncthreads(); }
  ghi = red[0]; __syncthreads();
  float wid = ghi - glo;
  glo -= 1e-3f * wid + 1e-20f;
  ghi += 1e-3f * wid + 1e-20f;

  // bisection: thread t finds the t-th smallest eigenvalue
  if (t < PD) {
    float lo = glo, hi = ghi;
    for (int it = 0; it < 42; ++it) {
      float mid = 0.5f * (lo + hi);
      if (mid <= lo || mid >= hi) break;     // fp32-converged
      int cnt = 0;
      float q = 1.0f;
      for (int i = 0; i < PD; ++i) {
        float term = (i > 0) ? e2[i - 1] * __builtin_amdgcn_rcpf(q) : 0.0f;
        q = (dd[i] - mid) - term;
        cnt += (q < 0.f);
        float aq = fabsf(q);
        if (aq < 1e-30f) q = (q < 0.f) ? -1e-30f : 1e-30f;
      }
      if (cnt > t) hi = mid; else lo = mid;
    }
    sig[t] = 0.5f * (lo + hi);
  }
  __syncthreads();

  // threshold search (mirror of the reference's vectorized loop)
  if (t == 0) {
    float c = 0.f;
    for (int i = 0; i < PD; ++i) { c += sig[i]; csum[i] = c; }
  }
  __syncthreads();
  float tau = 0.f;
  int vk = 1 << 30;
  if (t < PD) {
    int L = PD - 1 - t;
    tau = (L > 0) ? csum[L - 1] / (float)L : 0.0f;
    int gt = 0, lt2 = 0;
    for (int j = 0; j < L; ++j) {
      float sv = sig[j];
      gt  += (sv > tau);
      lt2 += (sv < tau);
    }
    if (gt == lt2) vk = t;
  }
  redi[t] = vk; __syncthreads();
  for (int s = 128; s > 0; s >>= 1) { if (t < s) redi[t] = min(redi[t], redi[t + s]); __syncthreads(); }
  if (t == redi[0]) out[b] = sqrtf(fmaxf(tau, 0.f));
}

extern "C" void kernel_launch(void* const* d_in, const int* in_sizes, int n_in,
                              void* d_out, int out_size, void* d_ws, size_t ws_size,
                              hipStream_t stream) {
  const float* x = (const float*)d_in[0];
  float* out = (float*)d_out;

  size_t gElems = (size_t)NB * PD * PD;       // 294912
  int CH = 64;
  while (CH > 1 && ws_size < ((size_t)CH + 1) * gElems * 4 + (size_t)NB * PD * 4)
    CH >>= 1;
  float* G = (float*)d_ws;
  float* partial = G + gElems;
  float* S = partial + (size_t)CH * gElems;
  int chunkSize = (NPATCH + CH - 1) / CH;

  row_sums_k<<<NB * PD, 256, 0, stream>>>(x, S);
  cov_gemm_k<<<NB * CH, 256, 0, stream>>>(x, partial, CH, chunkSize);
  reduce_fin_k<<<(int)((gElems + 255) / 256), 256, 0, stream>>>(partial, S, G, CH);
  eigen_k<<<NB, 256, 0, stream>>>(G, out);
}

// Round 3
// 851.374 us; speedup vs baseline: 1.7833x; 1.2977x over previous
//
#include <hip/hip_runtime.h>
#include <math.h>

#define NB 8          // batch
#define NC 3          // channels
#define PD 192        // feature dim = 3*8*8
#define IMG 512
#define NP 169        // patches per spatial dim
#define NPATCH 28561  // NP*NP
#define INV_N (1.0f/28561.0f)

typedef float f4 __attribute__((ext_vector_type(4)));
typedef f4 f4u __attribute__((aligned(4)));   // 4B-aligned vector load type

__device__ __forceinline__ float rdlane(float v, int lane) {
  return __uint_as_float(__builtin_amdgcn_readlane(__float_as_uint(v), lane));
}

// ---------------- per-feature patch sums (for the mean) ----------------
__global__ __launch_bounds__(256) void row_sums_k(const float* __restrict__ x,
                                                  float* __restrict__ S) {
  int bid = blockIdx.x;            // b*PD + d
  int b = bid / PD, d = bid - b * PD;
  int c = d >> 6, ii = (d >> 3) & 7, jj = d & 7;
  const float* img = x + ((size_t)(b * NC + c)) * (IMG * IMG);
  float part = 0.f;
  for (int p = threadIdx.x; p < NPATCH; p += 256) {
    int ph = p / NP;
    int pw = p - ph * NP;
    part += img[(3 * ph + ii) * IMG + 3 * pw + jj];
  }
  __shared__ float red[256];
  int t = threadIdx.x;
  red[t] = part; __syncthreads();
  for (int s = 128; s > 0; s >>= 1) { if (t < s) red[t] += red[t + s]; __syncthreads(); }
  if (t == 0) S[bid] = red[0];
}

// ---------------- split-K Gram matrix: partial[chunk][b][192][192] ----------------
__global__ __launch_bounds__(256, 2) void cov_gemm_k(const float* __restrict__ x,
                                                     float* __restrict__ partial,
                                                     int CH, int chunkSize) {
  int chunk = blockIdx.x % CH;
  int b = blockIdx.x / CH;
  int p0 = chunk * chunkSize;
  int pcount = NPATCH - p0;
  if (pcount > chunkSize) pcount = chunkSize;
  if (pcount < 0) pcount = 0;
  int ntiles = (pcount + 15) >> 4;
  int pend = p0 + pcount;

  __shared__ float As[16][200];    // [k-slice][192 features + pad]

  int t = threadIdx.x;
  int ty = t >> 4, tx = t & 15;
  const float* imgb = x + (size_t)b * NC * IMG * IMG;

  float acc[12][12];
  for (int i = 0; i < 12; ++i)
    for (int j = 0; j < 12; ++j)
      acc[i][j] = 0.f;

  for (int kt = 0; kt < ntiles; ++kt) {
    int pbase = p0 + (kt << 4);
    f4 ld[3];
    int pks[3], dls[3];
#pragma unroll
    for (int l = 0; l < 3; ++l) {
      int f = l * 256 + t;          // 0..767 quad index
      int pk = f / 48;              // 0..15 patch within k-tile
      int rr = f - pk * 48;         // 0..47
      int c  = rr >> 4;             // channel
      int ii = (rr & 15) >> 1;      // patch row offset 0..7
      int j4 = (rr & 1) << 2;       // 0 or 4
      int p = pbase + pk;
      f4 v = {0.f, 0.f, 0.f, 0.f};
      if (p < pend) {
        int ph = p / NP, pw = p - ph * NP;
        const f4u* src = (const f4u*)(imgb + ((size_t)c * IMG + (3 * ph + ii)) * IMG + 3 * pw + j4);
        v = (f4)(*src);
      }
      ld[l] = v;
      pks[l] = pk;
      dls[l] = (c << 6) + (ii << 3) + j4;
    }
    __syncthreads();
#pragma unroll
    for (int l = 0; l < 3; ++l)
      *(f4*)&As[pks[l]][dls[l]] = ld[l];
    __syncthreads();

    for (int kk = 0; kk < 16; ++kk) {
      const f4* ap = (const f4*)&As[kk][ty * 12];
      const f4* bp = (const f4*)&As[kk][tx * 12];
      f4 avq[3], bvq[3];
#pragma unroll
      for (int q = 0; q < 3; ++q) { avq[q] = ap[q]; bvq[q] = bp[q]; }
      float a[12], bb[12];
#pragma unroll
      for (int q = 0; q < 12; ++q) { a[q] = avq[q >> 2][q & 3]; bb[q] = bvq[q >> 2][q & 3]; }
#pragma unroll
      for (int i = 0; i < 12; ++i)
#pragma unroll
        for (int j = 0; j < 12; ++j)
          acc[i][j] += a[i] * bb[j];
    }
  }

  float* outp = partial + ((size_t)chunk * NB + b) * PD * PD;
  for (int i = 0; i < 12; ++i) {
    int m = ty * 12 + i;
    for (int j = 0; j < 12; ++j)
      outp[m * PD + tx * 12 + j] = acc[i][j];
  }
}

// ---------------- reduce partials + finalize covariance ----------------
__global__ __launch_bounds__(256) void reduce_fin_k(const float* __restrict__ partial,
                                                    const float* __restrict__ S,
                                                    float* __restrict__ G, int CH) {
  int e = blockIdx.x * 256 + threadIdx.x;
  const int tot = NB * PD * PD;
  if (e >= tot) return;
  int b = e / (PD * PD);
  int rem = e - b * PD * PD;
  int i = rem / PD, j = rem - i * PD;
  float s = 0.f;
  for (int c = 0; c < CH; ++c) s += partial[((size_t)c * NB + b) * PD * PD + rem];
  float mui = S[b * PD + i] * INV_N, muj = S[b * PD + j] * INV_N;
  G[e] = s * INV_N - mui * muj;
}

// ---------------- eigenvalues: register-resident Householder tridiag ----------------
// v3: A lives in VGPRs (12 waves; wave w owns cols [16w,16w+16), lane owns rows
// {l, l+64, l+128} -> 3x4 f4 frag). v/w vectors via LDS; column broadcast via
// v_readlane (off the LDS port). 3 barriers/step. Then Sturm bisection + threshold.
__global__ __launch_bounds__(768, 3) void eigen_k(const float* __restrict__ sigma,
                                                  float* __restrict__ out) {
  __shared__ float ppw[12][PD];     // per-wave matvec partials (unscaled)
  __shared__ float vvg[2][PD];      // v, double-buffered by step parity, zero-padded
  __shared__ float wwg[PD];         // w vector
  __shared__ float red0[2];         // beta per parity
  __shared__ float red2[12];        // per-wave v^T A v partials
  __shared__ float dd[PD], ee[PD], e2[PD];
  __shared__ float sig[PD], csum[PD];
  __shared__ float grd[8];
  __shared__ int   redi[4];

  int b = blockIdx.x, t = threadIdx.x;
  int w = t >> 6, l = t & 63;
  int colbase = w << 4;
  const float* M = sigma + (size_t)b * PD * PD;

  // load fragment (strided f4 global reads; matrix is L2-resident)
  f4 a[3][4];
#pragma unroll
  for (int rr = 0; rr < 3; ++rr) {
    const float* mp = M + (size_t)((rr << 6) + l) * PD + colbase;
#pragma unroll
    for (int cc = 0; cc < 4; ++cc)
      a[rr][cc] = *(const f4*)(mp + (cc << 2));
  }

  // prep(c): owning wave extracts column c (span [c+1,PD)), computes alpha/beta,
  // writes v into vvg[c&1] (full coverage: zeros below head), ee[c], red0[c&1].
  auto prep = [&](int c) {
    int wown = c >> 4;
    if (w == wown) {
      int k1 = c + 1;
      float av[3] = {0.f, 0.f, 0.f};
#pragma unroll
      for (int cc = 0; cc < 4; ++cc)
#pragma unroll
        for (int e = 0; e < 4; ++e) {
          if (colbase + (cc << 2) + e == c) {   // wave-uniform guard
            av[0] = a[0][cc][e]; av[1] = a[1][cc][e]; av[2] = a[2][cc][e];
          }
        }
      float am[3];
#pragma unroll
      for (int rr = 0; rr < 3; ++rr) {
        int row = (rr << 6) + l;
        am[rr] = (row >= k1) ? av[rr] : 0.f;
      }
      float sq = am[0] * am[0] + am[1] * am[1] + am[2] * am[2];
#pragma unroll
      for (int off = 32; off; off >>= 1) sq += __shfl_xor(sq, off, 64);
      int slot = k1 >> 6;                        // uniform
      float tmp = (slot == 0) ? av[0] : (slot == 1) ? av[1] : av[2];
      float x0 = rdlane(tmp, k1 & 63);
      float nrm = sqrtf(sq);
      float alpha = (x0 >= 0.f) ? -nrm : nrm;
      bool degen = (sq < 1e-32f);
      float beta = degen ? 0.f : 1.0f / (sq - alpha * x0);
      int par = c & 1;
      if (l == 0) {
        red0[par] = beta;
        ee[c] = degen ? x0 : alpha;
      }
      float head = x0 - alpha;
#pragma unroll
      for (int rr = 0; rr < 3; ++rr) {
        int row = (rr << 6) + l;
        vvg[par][row] = (row < k1) ? 0.f : (row == k1) ? head : am[rr];
      }
    }
  };

  prep(0);
  __syncthreads();

  for (int k = 0; k < PD - 2; ++k) {
    int cur = k & 1;
    int k1 = k + 1;

    // ---- Phase A: p_raw = A*v (per-wave column-slice), v^T A v partial ----
    float vr[3], acc[3], sv[16];
#pragma unroll
    for (int rr = 0; rr < 3; ++rr) vr[rr] = vvg[cur][(rr << 6) + l];
    {
      int slot = w >> 2;                         // uniform
      float src = (slot == 0) ? vr[0] : (slot == 1) ? vr[1] : vr[2];
      int lbase = (w & 3) << 4;
#pragma unroll
      for (int j = 0; j < 16; ++j) sv[j] = rdlane(src, lbase + j);
    }
#pragma unroll
    for (int rr = 0; rr < 3; ++rr) {
      float s = 0.f;
#pragma unroll
      for (int cc = 0; cc < 4; ++cc)
#pragma unroll
        for (int e = 0; e < 4; ++e)
          s += sv[(cc << 2) + e] * a[rr][cc][e];
      acc[rr] = s;
      ppw[w][(rr << 6) + l] = s;
    }
    float dp = vr[0] * acc[0] + vr[1] * acc[1] + vr[2] * acc[2];
#pragma unroll
    for (int off = 32; off; off >>= 1) dp += __shfl_xor(dp, off, 64);
    if (l == 0) red2[w] = dp;
    __syncthreads();                             // B1

    // ---- Phase B (threads<192): w = beta*p - Kc*v, masked ----
    if (t < PD) {
      float beta = red0[cur];
      float s = 0.f;
#pragma unroll
      for (int j = 0; j < 12; ++j) s += ppw[j][t];
      float vt = 0.f;
#pragma unroll
      for (int j = 0; j < 12; ++j) vt += red2[j];
      float p = beta * s;
      float Kc = 0.5f * beta * beta * vt;
      wwg[t] = (t >= k1) ? (p - Kc * vvg[cur][t]) : 0.f;
    }
    __syncthreads();                             // B2

    // ---- Phase C: rank-2 update (registers) + prep next column ----
    float wr[3], sw[16];
#pragma unroll
    for (int rr = 0; rr < 3; ++rr) wr[rr] = wwg[(rr << 6) + l];
    {
      int slot = w >> 2;
      float srcw = (slot == 0) ? wr[0] : (slot == 1) ? wr[1] : wr[2];
      int lbase = (w & 3) << 4;
#pragma unroll
      for (int j = 0; j < 16; ++j) sw[j] = rdlane(srcw, lbase + j);
    }
#pragma unroll
    for (int rr = 0; rr < 3; ++rr) {
      float vrr = vr[rr], wrr = wr[rr];
#pragma unroll
      for (int cc = 0; cc < 4; ++cc)
#pragma unroll
        for (int e = 0; e < 4; ++e) {
          int j = (cc << 2) + e;
          a[rr][cc][e] -= vrr * sw[j] + wrr * sv[j];
        }
    }
    prep(k + 1);
    __syncthreads();                             // B3
  }

  // ---- extract diagonal ----
#pragma unroll
  for (int rr = 0; rr < 3; ++rr) {
    int row = (rr << 6) + l;
#pragma unroll
    for (int cc = 0; cc < 4; ++cc)
#pragma unroll
      for (int e = 0; e < 4; ++e)
        if (colbase + (cc << 2) + e == row) dd[row] = a[rr][cc][e];
  }
  __syncthreads();

  if (t < PD - 1) e2[t] = ee[t] * ee[t];

  // Gershgorin bounds (threads<192 + shuffle)
  float glo = 1e30f, ghi = -1e30f;
  if (t < PD) {
    float r = 0.f;
    if (t > 0) r += fabsf(ee[t - 1]);
    if (t < PD - 1) r += fabsf(ee[t]);
    glo = dd[t] - r;
    ghi = dd[t] + r;
  }
#pragma unroll
  for (int off = 32; off; off >>= 1) {
    glo = fminf(glo, __shfl_xor(glo, off, 64));
    ghi = fmaxf(ghi, __shfl_xor(ghi, off, 64));
  }
  if (l == 0 && w < 3) { grd[w] = glo; grd[4 + w] = ghi; }
  __syncthreads();
  float gl = fminf(grd[0], fminf(grd[1], grd[2]));
  float gh = fmaxf(grd[4], fmaxf(grd[5], grd[6]));
  float wid = gh - gl;
  gl -= 1e-3f * wid + 1e-20f;
  gh += 1e-3f * wid + 1e-20f;

  // bisection: thread t finds the t-th smallest eigenvalue
  if (t < PD) {
    float lo = gl, hi = gh;
    for (int it = 0; it < 42; ++it) {
      float mid = 0.5f * (lo + hi);
      if (mid <= lo || mid >= hi) break;     // fp32-converged
      int cnt = 0;
      float q = 1.0f;
      for (int i = 0; i < PD; ++i) {
        float term = (i > 0) ? e2[i - 1] * __builtin_amdgcn_rcpf(q) : 0.0f;
        q = (dd[i] - mid) - term;
        cnt += (q < 0.f);
        float aq = fabsf(q);
        if (aq < 1e-30f) q = (q < 0.f) ? -1e-30f : 1e-30f;
      }
      if (cnt > t) hi = mid; else lo = mid;
    }
    sig[t] = 0.5f * (lo + hi);
  }
  __syncthreads();

  // threshold search (mirror of the reference's vectorized loop)
  if (t == 0) {
    float c = 0.f;
    for (int i = 0; i < PD; ++i) { c += sig[i]; csum[i] = c; }
  }
  __syncthreads();
  float tau = 0.f;
  int vk = 1 << 30;
  if (t < PD) {
    int L = PD - 1 - t;
    tau = (L > 0) ? csum[L - 1] / (float)L : 0.0f;
    int gt = 0, lt2 = 0;
    for (int j = 0; j < L; ++j) {
      float svv = sig[j];
      gt  += (svv > tau);
      lt2 += (svv < tau);
    }
    if (gt == lt2) vk = t;
  }
#pragma unroll
  for (int off = 32; off; off >>= 1) vk = min(vk, __shfl_xor(vk, off, 64));
  if (l == 0 && w < 3) redi[w] = vk;
  __syncthreads();
  if (t == 0) {
    int g = min(redi[0], min(redi[1], redi[2]));
    redi[3] = (g == (1 << 30)) ? 0 : g;   // reference: argmax of all-false = 0
  }
  __syncthreads();
  if (t < PD && t == redi[3]) out[b] = sqrtf(fmaxf(tau, 0.f));
}

extern "C" void kernel_launch(void* const* d_in, const int* in_sizes, int n_in,
                              void* d_out, int out_size, void* d_ws, size_t ws_size,
                              hipStream_t stream) {
  const float* x = (const float*)d_in[0];
  float* out = (float*)d_out;

  size_t gElems = (size_t)NB * PD * PD;       // 294912
  int CH = 64;
  while (CH > 1 && ws_size < ((size_t)CH + 1) * gElems * 4 + (size_t)NB * PD * 4)
    CH >>= 1;
  float* G = (float*)d_ws;
  float* partial = G + gElems;
  float* S = partial + (size_t)CH * gElems;
  int chunkSize = (NPATCH + CH - 1) / CH;

  row_sums_k<<<NB * PD, 256, 0, stream>>>(x, S);
  cov_gemm_k<<<NB * CH, 256, 0, stream>>>(x, partial, CH, chunkSize);
  reduce_fin_k<<<(int)((gElems + 255) / 256), 256, 0, stream>>>(partial, S, G, CH);
  eigen_k<<<NB, 768, 0, stream>>>(G, out);
}